// Round 5
// baseline (98.732 us; speedup 1.0000x reference)
//
#include <hip/hip_runtime.h>

typedef __attribute__((ext_vector_type(8))) short bf16x8;
typedef __attribute__((ext_vector_type(4))) float f32x4;

#define NATOMS 65536
#define NIN 256
#define NHID 512
#define TM 64

__device__ __forceinline__ unsigned short f2b(float f) {
    union { float f; unsigned int u; } a; a.f = f;
    unsigned int r = a.u + 0x7FFFu + ((a.u >> 16) & 1u);
    return (unsigned short)(r >> 16);
}
__device__ __forceinline__ float b2f(unsigned short h) {
    union { unsigned int u; float f; } a; a.u = ((unsigned int)h) << 16;
    return a.f;
}
__device__ __forceinline__ float fast_tanh(float v) {
    float e = __expf(2.f * v);
    return 1.f - 2.f / (e + 1.f);
}

__global__ void cvt_kernel(const float* __restrict__ W1, const float* __restrict__ W2,
                           const float* __restrict__ W3,
                           unsigned short* __restrict__ W1b, unsigned short* __restrict__ W2b,
                           unsigned short* __restrict__ W3b) {
    int i = blockIdx.x * blockDim.x + threadIdx.x;
    const int n1 = 4 * NHID * NIN;    // 524288
    const int n2 = 4 * NHID * NHID;   // 1048576
    const int n3 = 4 * NHID;          // 2048
    if (i < n1) W1b[i] = f2b(W1[i]);
    if (i < n2) W2b[i] = f2b(W2[i]);
    if (i < n3) W3b[i] = f2b(W3[i]);
}

// Hierarchical compaction: wave ballot -> LDS atomics (16/block) -> 4 global
// atomics per block. Replaces 65536 contended global atomics on 4 addresses.
__global__ __launch_bounds__(1024) void compact_kernel(
    const int* __restrict__ z, int* __restrict__ cnt,
    int* __restrict__ lists, float* __restrict__ out) {
    __shared__ int lcnt[4];          // per-block species counts
    __shared__ int gbase[4];         // block's reserved base in global list
    __shared__ int wbase[16][4];     // per-wave base within block

    int tid = threadIdx.x;
    int wv = tid >> 6;
    int lane = tid & 63;
    if (tid < 4) lcnt[tid] = 0;
    __syncthreads();

    int i = blockIdx.x * 1024 + tid;
    int zz = z[i];
    int s = (zz == 1) ? 0 : (zz == 6) ? 1 : (zz == 7) ? 2 : (zz == 8) ? 3 : -1;
    if (s < 0) out[i] = 0.f;

    int prefix = 0;
#pragma unroll
    for (int sp = 0; sp < 4; ++sp) {
        unsigned long long m = __ballot(s == sp);
        if (m) {
            int c = __popcll(m);
            int leader = __ffsll((long long)m) - 1;
            if (lane == leader) wbase[wv][sp] = atomicAdd(&lcnt[sp], c);
            if (s == sp) prefix = __popcll(m & ((1ull << lane) - 1ull));
        }
    }
    __syncthreads();
    if (tid < 4) gbase[tid] = atomicAdd(&cnt[tid], lcnt[tid]);
    __syncthreads();

    if (s >= 0) lists[s * NATOMS + gbase[s] + wbase[wv][s] + prefix] = i;
}

// NT = number of 16-col N-tiles this wave owns.
template<int K, int LDB, int NT>
__device__ __forceinline__ void gemm_layer(const char* lds, const unsigned short* Wrow,
                                           int lane, int ncb, f32x4 acc[4][NT]) {
    for (int k0 = 0; k0 < K; k0 += 32) {
        bf16x8 a[4];
#pragma unroll
        for (int mt = 0; mt < 4; ++mt) {
            int row = mt * 16 + (lane & 15);
            int colb = (k0 + ((lane >> 4) << 3)) * 2;
            a[mt] = *(const bf16x8*)(lds + row * LDB + (colb ^ ((row & 7) << 4)));
        }
        bf16x8 bfr[NT];
#pragma unroll
        for (int nt = 0; nt < NT; ++nt) {
            int n = ncb + nt * 16 + (lane & 15);
            bfr[nt] = *(const bf16x8*)(Wrow + (size_t)n * K + k0 + ((lane >> 4) << 3));
        }
#pragma unroll
        for (int nt = 0; nt < NT; ++nt)
#pragma unroll
            for (int mt = 0; mt < 4; ++mt)
                acc[mt][nt] = __builtin_amdgcn_mfma_f32_16x16x32_bf16(a[mt], bfr[nt], acc[mt][nt], 0, 0, 0);
    }
}

template<int LDB, int NT>
__device__ __forceinline__ void act_store(char* ldsOut, const float* __restrict__ bias,
                                          int lane, int ncb, f32x4 acc[4][NT]) {
#pragma unroll
    for (int nt = 0; nt < NT; ++nt) {
        int n = ncb + nt * 16 + (lane & 15);
        float bv = bias[n];
#pragma unroll
        for (int mt = 0; mt < 4; ++mt) {
#pragma unroll
            for (int r = 0; r < 4; ++r) {
                int row = mt * 16 + ((lane >> 4) << 2) + r;
                float v = fast_tanh(acc[mt][nt][r] + bv);
                *(unsigned short*)(ldsOut + row * LDB + (((n * 2) ^ ((row & 7) << 4)))) = f2b(v);
            }
        }
    }
}

// 512 threads = 8 waves. Single 64 KB LDS buffer (x-tile overwritten by h1
// after layer-1 GEMM completes) -> 2 blocks/CU, all ~456 active blocks
// co-resident in one round, 4 waves/SIMD for latency hiding.
__global__ __launch_bounds__(512, 4) void mlp_kernel(
    const float* __restrict__ x, const int* __restrict__ cnt, const int* __restrict__ lists,
    const unsigned short* __restrict__ W1b, const unsigned short* __restrict__ W2b,
    const unsigned short* __restrict__ W3b,
    const float* __restrict__ b1, const float* __restrict__ b2, const float* __restrict__ b3,
    float* __restrict__ out) {
    int bx = blockIdx.x;
    int s = bx & 3;         // species fixed per XCD (bx%8 -> XCD): weights stay hot in its L2
    int t = bx >> 2;
    int base = t * TM;
    int n_s = cnt[s];
    if (base >= n_s) return;
    const int* list = lists + s * NATOMS;
    int cnt_t = n_s - base; if (cnt_t > TM) cnt_t = TM;

    __shared__ __align__(16) char lds[TM * NHID * 2];   // 64 KB: x-tile, then h1, then h2

    int tid = threadIdx.x;
    int lane = tid & 63;
    int w = tid >> 6;            // 0..7
    int ncb = w * 64;

    // ---- gather x rows -> bf16 LDS (swizzled, LDB=512): 512 thr, 8 float4 each ----
    {
        int r = tid >> 3;            // 0..63 (tile row)
        int cb = (tid & 7) * 32;     // col base (floats)
        int atom = (r < cnt_t) ? list[base + r] : -1;
        const float* xr = x + (size_t)(atom < 0 ? 0 : atom) * NIN;
#pragma unroll
        for (int j = 0; j < 8; ++j) {
            int c = cb + j * 4;
            float4 v;
            if (atom >= 0) v = *(const float4*)(xr + c);
            else v = make_float4(0.f, 0.f, 0.f, 0.f);
            unsigned short p[4] = { f2b(v.x), f2b(v.y), f2b(v.z), f2b(v.w) };
            int off = r * (NIN * 2) + (((c * 2) ^ ((r & 7) << 4)));
            *(unsigned long long*)(lds + off) = *(unsigned long long*)p;
        }
    }
    __syncthreads();

    // ---- layer 1: [64x256] x [256x512]^T -> h1 (acc in regs) ----
    {
        f32x4 acc[4][4];
#pragma unroll
        for (int i = 0; i < 4; ++i)
#pragma unroll
            for (int j = 0; j < 4; ++j) acc[i][j] = (f32x4){0.f, 0.f, 0.f, 0.f};
        gemm_layer<NIN, NIN * 2, 4>(lds, W1b + (size_t)s * NHID * NIN, lane, ncb, acc);
        __syncthreads();   // all waves done reading x-tile before h1 overwrites it
        act_store<NHID * 2, 4>(lds, b1 + s * NHID, lane, ncb, acc);
    }
    __syncthreads();

    // ---- layer 2: [64x512] x [512x512]^T -> h2 (in place) ----
    {
        f32x4 acc[4][4];
#pragma unroll
        for (int i = 0; i < 4; ++i)
#pragma unroll
            for (int j = 0; j < 4; ++j) acc[i][j] = (f32x4){0.f, 0.f, 0.f, 0.f};
        gemm_layer<NHID, NHID * 2, 4>(lds, W2b + (size_t)s * NHID * NHID, lane, ncb, acc);
        __syncthreads();   // all reads of h1 done before overwrite
        act_store<NHID * 2, 4>(lds, b2 + s * NHID, lane, ncb, acc);
    }
    __syncthreads();

    // ---- layer 3: out[m] = dot(h2[m,:], W3[s]) + b3[s] ----
    {
        int m = tid >> 3;        // 0..63
        int q = tid & 7;         // 64-col eighth
        const unsigned short* W3s = W3b + (size_t)s * NHID;
        float sum = 0.f;
#pragma unroll
        for (int j = 0; j < 8; ++j) {
            int hh = q * 64 + j * 8;
            int off = m * (NHID * 2) + (((hh * 2) ^ ((m & 7) << 4)));
            bf16x8 hv = *(const bf16x8*)(lds + off);
            bf16x8 wv = *(const bf16x8*)(W3s + hh);
#pragma unroll
            for (int e = 0; e < 8; ++e)
                sum += b2f((unsigned short)hv[e]) * b2f((unsigned short)wv[e]);
        }
        sum += __shfl_xor(sum, 1);
        sum += __shfl_xor(sum, 2);
        sum += __shfl_xor(sum, 4);
        if (q == 0 && m < cnt_t) out[list[base + m]] = sum + b3[s];
    }
}

extern "C" void kernel_launch(void* const* d_in, const int* in_sizes, int n_in,
                              void* d_out, int out_size, void* d_ws, size_t ws_size,
                              hipStream_t stream) {
    const float* x  = (const float*)d_in[0];
    const int*   z  = (const int*)d_in[1];
    const float* W1 = (const float*)d_in[2];
    const float* b1 = (const float*)d_in[3];
    const float* W2 = (const float*)d_in[4];
    const float* b2 = (const float*)d_in[5];
    const float* W3 = (const float*)d_in[6];
    const float* b3 = (const float*)d_in[7];
    float* out = (float*)d_out;

    char* ws = (char*)d_ws;
    int* cnt = (int*)ws;                                      // 16 B
    int* lists = (int*)(ws + 256);                            // 4*65536*4 = 1 MB
    unsigned short* W1b = (unsigned short*)(ws + 256 + (size_t)4 * NATOMS * 4);
    unsigned short* W2b = W1b + 4 * NHID * NIN;
    unsigned short* W3b = W2b + 4 * NHID * NHID;

    hipMemsetAsync(cnt, 0, 16, stream);
    cvt_kernel<<<4096, 256, 0, stream>>>(W1, W2, W3, W1b, W2b, W3b);
    compact_kernel<<<NATOMS / 1024, 1024, 0, stream>>>(z, cnt, lists, out);
    mlp_kernel<<<4096, 512, 0, stream>>>(x, cnt, lists, W1b, W2b, W3b, b1, b2, b3, out);
}

// Round 6
// 73.787 us; speedup vs baseline: 1.3381x; 1.3381x over previous
//
#include <hip/hip_runtime.h>

typedef __attribute__((ext_vector_type(8))) short bf16x8;
typedef __attribute__((ext_vector_type(4))) float f32x4;
typedef unsigned short us;

#define NATOMS 65536
#define NIN 256
#define NHID 512
#define TM 32

__device__ __forceinline__ us f2b(float f) {
    union { float f; unsigned int u; } a; a.f = f;
    unsigned int r = a.u + 0x7FFFu + ((a.u >> 16) & 1u);
    return (us)(r >> 16);
}
__device__ __forceinline__ float b2f(us h) {
    union { unsigned int u; float f; } a; a.u = ((unsigned int)h) << 16;
    return a.f;
}
__device__ __forceinline__ float fast_tanh(float v) {
    float e = __expf(2.f * v);
    return 1.f - 2.f / (e + 1.f);
}

// Pack W1/W2 into MFMA-fragment order: chunk[(ntile*KS + kstep)*64 + lane] =
// W[n= ntile*16+(lane&15)][k= kstep*32+(lane>>4)*8 .. +8) as bf16x8.
// A wave's B-fragment load is then one coalesced 1 KB transaction.
__global__ void cvt_kernel(const float* __restrict__ W1, const float* __restrict__ W2,
                           const float* __restrict__ W3,
                           us* __restrict__ W1p, us* __restrict__ W2p,
                           us* __restrict__ W3b) {
    int i = blockIdx.x * blockDim.x + threadIdx.x;
    if (i < 65536) {               // W1: 4 species * 32 ntiles * 8 ksteps * 64 lanes
        int s = i >> 14, rem = i & 16383;
        int ntile = rem >> 9, r2 = rem & 511;
        int kstep = r2 >> 6, lane = r2 & 63;
        int n = ntile * 16 + (lane & 15);
        int k = kstep * 32 + ((lane >> 4) << 3);
        const float* src = W1 + ((size_t)(s * NHID + n) * NIN + k);
        us p[8];
#pragma unroll
        for (int j = 0; j < 8; ++j) p[j] = f2b(src[j]);
        *(uint4*)(W1p + (size_t)i * 8) = *(uint4*)p;
    }
    if (i < 131072) {              // W2: 4 * 32 * 16 * 64
        int s = i >> 15, rem = i & 32767;
        int ntile = rem >> 10, r2 = rem & 1023;
        int kstep = r2 >> 6, lane = r2 & 63;
        int n = ntile * 16 + (lane & 15);
        int k = kstep * 32 + ((lane >> 4) << 3);
        const float* src = W2 + ((size_t)(s * NHID + n) * NHID + k);
        us p[8];
#pragma unroll
        for (int j = 0; j < 8; ++j) p[j] = f2b(src[j]);
        *(uint4*)(W2p + (size_t)i * 8) = *(uint4*)p;
    }
    if (i < 2048) W3b[i] = f2b(W3[i]);   // layer-3 stays linear
}

// Hierarchical compaction: wave ballot -> LDS atomics -> 4 global atomics/block.
__global__ __launch_bounds__(1024) void compact_kernel(
    const int* __restrict__ z, int* __restrict__ cnt,
    int* __restrict__ lists, float* __restrict__ out) {
    __shared__ int lcnt[4];
    __shared__ int gbase[4];
    __shared__ int wbase[16][4];

    int tid = threadIdx.x;
    int wv = tid >> 6;
    int lane = tid & 63;
    if (tid < 4) lcnt[tid] = 0;
    __syncthreads();

    int i = blockIdx.x * 1024 + tid;
    int zz = z[i];
    int s = (zz == 1) ? 0 : (zz == 6) ? 1 : (zz == 7) ? 2 : (zz == 8) ? 3 : -1;
    if (s < 0) out[i] = 0.f;

    int prefix = 0;
#pragma unroll
    for (int sp = 0; sp < 4; ++sp) {
        unsigned long long m = __ballot(s == sp);
        if (m) {
            int c = __popcll(m);
            int leader = __ffsll((long long)m) - 1;
            if (lane == leader) wbase[wv][sp] = atomicAdd(&lcnt[sp], c);
            if (s == sp) prefix = __popcll(m & ((1ull << lane) - 1ull));
        }
    }
    __syncthreads();
    if (tid < 4) gbase[tid] = atomicAdd(&cnt[tid], lcnt[tid]);
    __syncthreads();

    if (s >= 0) lists[s * NATOMS + gbase[s] + wbase[wv][s] + prefix] = i;
}

// MT=2 M-tiles (32 rows), NT=4 N-tiles (64 cols) per wave. Packed-B pointers.
template<int K, int LDB, int NT>
__device__ __forceinline__ void gemm_layer(const char* lds, const us* Wp,
                                           int lane, int wtile, f32x4 acc[2][NT]) {
    constexpr int KS = K / 32;
    const us* wptr[NT];
#pragma unroll
    for (int nt = 0; nt < NT; ++nt)
        wptr[nt] = Wp + (((size_t)(wtile + nt) * KS) * 64 + lane) * 8;
    for (int k0 = 0; k0 < K; k0 += 32) {
        bf16x8 a[2];
#pragma unroll
        for (int mt = 0; mt < 2; ++mt) {
            int row = mt * 16 + (lane & 15);
            int colb = (k0 + ((lane >> 4) << 3)) * 2;
            a[mt] = *(const bf16x8*)(lds + row * LDB + (colb ^ ((row & 7) << 4)));
        }
        bf16x8 bfr[NT];
#pragma unroll
        for (int nt = 0; nt < NT; ++nt) {
            bfr[nt] = *(const bf16x8*)wptr[nt];
            wptr[nt] += 512;     // 64 chunks * 8 shorts per k-step
        }
#pragma unroll
        for (int nt = 0; nt < NT; ++nt)
#pragma unroll
            for (int mt = 0; mt < 2; ++mt)
                acc[mt][nt] = __builtin_amdgcn_mfma_f32_16x16x32_bf16(a[mt], bfr[nt], acc[mt][nt], 0, 0, 0);
    }
}

template<int LDB, int NT>
__device__ __forceinline__ void act_store(char* ldsOut, const float* __restrict__ bias,
                                          int lane, int ncb, f32x4 acc[2][NT]) {
#pragma unroll
    for (int nt = 0; nt < NT; ++nt) {
        int n = ncb + nt * 16 + (lane & 15);
        float bv = bias[n];
#pragma unroll
        for (int mt = 0; mt < 2; ++mt) {
#pragma unroll
            for (int r = 0; r < 4; ++r) {
                int row = mt * 16 + ((lane >> 4) << 2) + r;
                float v = fast_tanh(acc[mt][nt][r] + bv);
                *(us*)(ldsOut + row * LDB + (((n * 2) ^ ((row & 7) << 4)))) = f2b(v);
            }
        }
    }
}

// TM=32, 512 thr (8 waves), 32 KB LDS, acc[2][4]=32 VGPR -> no spill at
// launch_bounds(512,4) => 2 blocks/CU, 4 waves/SIMD.
__global__ __launch_bounds__(512, 4) void mlp_kernel(
    const float* __restrict__ x, const int* __restrict__ cnt, const int* __restrict__ lists,
    const us* __restrict__ W1p, const us* __restrict__ W2p, const us* __restrict__ W3b,
    const float* __restrict__ b1, const float* __restrict__ b2, const float* __restrict__ b3,
    float* __restrict__ out) {
    int bx = blockIdx.x;
    int s = bx & 3;
    int t = bx >> 2;
    int base = t * TM;
    int n_s = cnt[s];
    if (base >= n_s) return;
    const int* list = lists + s * NATOMS;
    int cnt_t = n_s - base; if (cnt_t > TM) cnt_t = TM;

    __shared__ __align__(16) char lds[TM * NHID * 2];   // 32 KB: x-tile, then h1, then h2

    int tid = threadIdx.x;
    int lane = tid & 63;
    int w = tid >> 6;            // 0..7
    int ncb = w * 64;
    int wtile = w * 4;           // base 16-col tile index

    // ---- gather x rows -> bf16 LDS (swizzled, LDB=512B): 16 thr/row, 4 float4 ----
    {
        int r = tid >> 4;            // 0..31
        int cb = (tid & 15) * 16;    // col base (floats)
        int atom = (r < cnt_t) ? list[base + r] : -1;
        const float* xr = x + (size_t)(atom < 0 ? 0 : atom) * NIN;
#pragma unroll
        for (int j = 0; j < 4; ++j) {
            int c = cb + j * 4;
            float4 v;
            if (atom >= 0) v = *(const float4*)(xr + c);
            else v = make_float4(0.f, 0.f, 0.f, 0.f);
            us p[4] = { f2b(v.x), f2b(v.y), f2b(v.z), f2b(v.w) };
            int off = r * (NIN * 2) + (((c * 2) ^ ((r & 7) << 4)));
            *(unsigned long long*)(lds + off) = *(unsigned long long*)p;
        }
    }
    __syncthreads();

    // ---- layer 1: [32x256] x [256x512]^T -> h1 ----
    {
        f32x4 acc[2][4];
#pragma unroll
        for (int i = 0; i < 2; ++i)
#pragma unroll
            for (int j = 0; j < 4; ++j) acc[i][j] = (f32x4){0.f, 0.f, 0.f, 0.f};
        gemm_layer<NIN, NIN * 2, 4>(lds, W1p + (size_t)s * NHID * NIN, lane, wtile, acc);
        __syncthreads();   // x-tile fully consumed before h1 overwrites it
        act_store<NHID * 2, 4>(lds, b1 + s * NHID, lane, ncb, acc);
    }
    __syncthreads();

    // ---- layer 2: [32x512] x [512x512]^T -> h2 (in place) ----
    {
        f32x4 acc[2][4];
#pragma unroll
        for (int i = 0; i < 2; ++i)
#pragma unroll
            for (int j = 0; j < 4; ++j) acc[i][j] = (f32x4){0.f, 0.f, 0.f, 0.f};
        gemm_layer<NHID, NHID * 2, 4>(lds, W2p + (size_t)s * NHID * NHID, lane, wtile, acc);
        __syncthreads();   // h1 fully consumed before h2 overwrites it
        act_store<NHID * 2, 4>(lds, b2 + s * NHID, lane, ncb, acc);
    }
    __syncthreads();

    // ---- layer 3: out[m] = dot(h2[m,:], W3[s]) + b3[s]; 16 thr/row ----
    {
        int m = tid >> 4;        // 0..31
        int q = tid & 15;        // 32-col slice
        const us* W3s = W3b + (size_t)s * NHID;
        float sum = 0.f;
#pragma unroll
        for (int j = 0; j < 4; ++j) {
            int hh = q * 32 + j * 8;
            int off = m * (NHID * 2) + (((hh * 2) ^ ((m & 7) << 4)));
            bf16x8 hv = *(const bf16x8*)(lds + off);
            bf16x8 wv = *(const bf16x8*)(W3s + hh);
#pragma unroll
            for (int e = 0; e < 8; ++e)
                sum += b2f((us)hv[e]) * b2f((us)wv[e]);
        }
        sum += __shfl_xor(sum, 1);
        sum += __shfl_xor(sum, 2);
        sum += __shfl_xor(sum, 4);
        sum += __shfl_xor(sum, 8);
        if (q == 0 && m < cnt_t) out[list[base + m]] = sum + b3[s];
    }
}

extern "C" void kernel_launch(void* const* d_in, const int* in_sizes, int n_in,
                              void* d_out, int out_size, void* d_ws, size_t ws_size,
                              hipStream_t stream) {
    const float* x  = (const float*)d_in[0];
    const int*   z  = (const int*)d_in[1];
    const float* W1 = (const float*)d_in[2];
    const float* b1 = (const float*)d_in[3];
    const float* W2 = (const float*)d_in[4];
    const float* b2 = (const float*)d_in[5];
    const float* W3 = (const float*)d_in[6];
    const float* b3 = (const float*)d_in[7];
    float* out = (float*)d_out;

    char* ws = (char*)d_ws;
    int* cnt = (int*)ws;                                      // 16 B
    int* lists = (int*)(ws + 256);                            // 1 MB
    us* W1p = (us*)(ws + 256 + (size_t)4 * NATOMS * 4);       // 1 MB
    us* W2p = W1p + 4 * NHID * NIN;                           // 2 MB
    us* W3b = W2p + 4 * NHID * NHID;                          // 4 KB

    hipMemsetAsync(cnt, 0, 16, stream);
    cvt_kernel<<<512, 256, 0, stream>>>(W1, W2, W3, W1p, W2p, W3b);
    compact_kernel<<<NATOMS / 1024, 1024, 0, stream>>>(z, cnt, lists, out);
    mlp_kernel<<<8192, 512, 0, stream>>>(x, cnt, lists, W1p, W2p, W3b, b1, b2, b3, out);
}